// Round 6
// baseline (370.859 us; speedup 1.0000x reference)
//
#include <hip/hip_runtime.h>

#define N_NODES 50000
#define N_EDGES 800000
#define DIM 128
#define K2 256          // concat K dimension (wt rows)
#define NREL 200
#define BNF 16          // nodes per fused block
#define NFB 3125        // fused blocks (50000/16)
#define ECAP6 768       // fused edge cache (16-node sum mean 256, +31 sigma)

typedef unsigned short u16;
typedef __attribute__((ext_vector_type(8))) short short8;   // 8 x bf16 = 4 VGPR
typedef __attribute__((ext_vector_type(4))) float f32x4;    // MFMA acc

__device__ __forceinline__ float bf2f(u16 v) {
    union { unsigned int u; float f; } x;
    x.u = ((unsigned int)v) << 16;
    return x.f;
}

__device__ __forceinline__ u16 f2bf(float f) {
    union { unsigned int u; float f; } x;
    x.f = f;
    return (u16)((x.u + 0x7FFFu + ((x.u >> 16) & 1u)) >> 16);  // RNE
}

// Per-wave dtype sniff (R2/R3-verified): fp32 inputs -> low mantissa halves
// parse as insane bf16 ~65%; bf16 N(0,1) data ~0%. Wave-uniform result.
__device__ __forceinline__ int sniff_fp32(const void* h, int tid) {
    const u16* hp = (const u16*)h;
    u16 v = hp[2 * (tid & 63)];
    float a = fabsf(bf2f(v));
    int insane = ((v & 0x7F80) == 0x7F80) || (a != 0.0f && (a > 1e6f || a < 1e-20f));
    return __popcll(__ballot(insane)) > 16;
}

// fused prep + per-node hist tail (R16: hist is now 50K-bin global atomics,
// ~16 hits/bin — no LDS hist, no coarse buckets).
#define PREP_H (N_NODES * 32)
#define PREP_R (NREL * 32)
#define PREP_W 8192
#define PREP_N (N_NODES / 4)
#define PREP_B 32
#define PREP_TOT (PREP_H + PREP_R + PREP_W + PREP_N + PREP_B)
#define PREP_BLOCKS ((PREP_TOT + 255) / 256)
#define HIST_BLOCKS 128
__global__ __launch_bounds__(256) void prep_hist(
    const void* __restrict__ h, const void* __restrict__ r, const void* __restrict__ norm,
    const void* __restrict__ W, const void* __restrict__ Wmsg, const void* __restrict__ bias,
    const int* __restrict__ dst,
    u16* __restrict__ hx, u16* __restrict__ r_bf, u16* __restrict__ wt,
    u16* __restrict__ norm_bf, float* __restrict__ b_f, int* __restrict__ nodeCount)
{
    int tid = threadIdx.x;
    if (blockIdx.x >= PREP_BLOCKS) {            // ---- per-node hist tail
        int stride = HIST_BLOCKS * 256;
        for (int e = (blockIdx.x - PREP_BLOCKS) * 256 + tid; e < N_EDGES; e += stride)
            atomicAdd(&nodeCount[dst[e]], 1);   // non-returning, fire-and-forget
        return;
    }
    int isf = sniff_fp32(h, tid);
    int t = blockIdx.x * 256 + tid;
    if (t < PREP_H) {
        int n = t >> 5, c = t & 31;
        float4 v; float nv;
        if (isf) {
            nv = ((const float*)norm)[n];
            v = *(const float4*)((const float*)h + (size_t)n * DIM + c * 4);
        } else {
            nv = bf2f(((const u16*)norm)[n]);
            ushort4 u = *(const ushort4*)((const u16*)h + (size_t)n * DIM + c * 4);
            v = make_float4(bf2f(u.x), bf2f(u.y), bf2f(u.z), bf2f(u.w));
        }
        ushort4 o;
        o.x = f2bf(v.x * nv); o.y = f2bf(v.y * nv); o.z = f2bf(v.z * nv); o.w = f2bf(v.w * nv);
        *(ushort4*)(hx + (size_t)n * DIM + c * 4) = o;
    } else if (t < PREP_H + PREP_R) {
        int t2 = t - PREP_H;
        int rho = t2 >> 5, c = t2 & 31;
        float4 v;
        if (isf) v = *(const float4*)((const float*)r + (size_t)rho * DIM + c * 4);
        else {
            ushort4 u = *(const ushort4*)((const u16*)r + (size_t)rho * DIM + c * 4);
            v = make_float4(bf2f(u.x), bf2f(u.y), bf2f(u.z), bf2f(u.w));
        }
        ushort4 o;
        o.x = f2bf(v.x); o.y = f2bf(v.y); o.z = f2bf(v.z); o.w = f2bf(v.w);
        *(ushort4*)(r_bf + (size_t)rho * DIM + c * 4) = o;
    } else if (t < PREP_H + PREP_R + PREP_W) {
        int t3 = t - PREP_H - PREP_R;
        int j = t3 >> 6;
        int k0 = (t3 & 63) * 4;
        ushort4 o;
        u16* op = (u16*)&o;
        for (int kk = 0; kk < 4; ++kk) {
            int k = k0 + kk;
            float wv;
            if (isf) wv = (k < 128) ? ((const float*)W)[(size_t)k * DIM + j]
                                    : ((const float*)Wmsg)[(size_t)(k - 128) * DIM + j];
            else     wv = (k < 128) ? bf2f(((const u16*)W)[(size_t)k * DIM + j])
                                    : bf2f(((const u16*)Wmsg)[(size_t)(k - 128) * DIM + j]);
            op[kk] = f2bf(wv);
        }
        *(ushort4*)(wt + (size_t)j * K2 + k0) = o;
    } else if (t < PREP_H + PREP_R + PREP_W + PREP_N) {
        int n0 = (t - PREP_H - PREP_R - PREP_W) * 4;
        ushort4 o;
        if (isf) {
            float4 v = *(const float4*)((const float*)norm + n0);
            o.x = f2bf(v.x); o.y = f2bf(v.y); o.z = f2bf(v.z); o.w = f2bf(v.w);
        } else {
            o = *(const ushort4*)((const u16*)norm + n0);
        }
        *(ushort4*)(norm_bf + n0) = o;
    } else if (t < PREP_TOT) {
        int j0 = (t - PREP_H - PREP_R - PREP_W - PREP_N) * 4;
        float4 v;
        if (isf) v = *(const float4*)((const float*)bias + j0);
        else {
            ushort4 u = *(const ushort4*)((const u16*)bias + j0);
            v = make_float4(bf2f(u.x), bf2f(u.y), bf2f(u.z), bf2f(u.w));
        }
        *(float4*)(b_f + j0) = v;
    }
}

// R16: exclusive scan of 50K node counts in ONE 1024-thread block.
// Thread t owns a 49-element chunk: local sum -> block scan -> re-walk chunk
// writing nodeBase + cursor (two global passes, L2-hot; no big reg arrays).
#define CPT 49   // 1024 * 49 = 50176 >= 50000
__global__ __launch_bounds__(1024) void node_scan(
    const int* __restrict__ nodeCount, int* __restrict__ nodeBase,
    int* __restrict__ cursor)
{
    __shared__ int sd[1024];
    int t = threadIdx.x;
    int s0 = t * CPT;
    int s1 = s0 + CPT; if (s1 > N_NODES) s1 = N_NODES;
    int ls = 0;
    for (int i = s0; i < s1; ++i) ls += nodeCount[i];
    sd[t] = ls;
    __syncthreads();
    for (int off = 1; off < 1024; off <<= 1) {
        int v = (t >= off) ? sd[t - off] : 0;
        __syncthreads();
        sd[t] += v;
        __syncthreads();
    }
    int run = sd[t] - ls;                 // exclusive base of this chunk
    for (int i = s0; i < s1; ++i) {
        nodeBase[i] = run;
        cursor[i] = run;
        run += nodeCount[i];
    }
    if (t == 0) nodeBase[N_NODES] = N_EDGES;
}

// R16: direct counting-sort scatter. One streaming pass, no barriers/LDS.
// pos = cursor[dst]++ (global returning atomic, ~16 hits/counter).
// payload = src | rel<<16 (dst bits no longer needed downstream).
#define SEB 1024  // edges per block (256 thr x 4)
__global__ __launch_bounds__(256) void scatter(
    const int* __restrict__ dst, const int* __restrict__ src,
    const int* __restrict__ rel, int* __restrict__ cursor, int* __restrict__ spk)
{
    int e0 = blockIdx.x * SEB + threadIdx.x;
#pragma unroll
    for (int i = 0; i < 4; ++i) {
        int e = e0 + i * 256;
        if (e < N_EDGES) {
            int pos = atomicAdd(&cursor[dst[e]], 1);
            spk[pos] = (src[e] & 0xFFFF) | (rel[e] << 16);
        }
    }
}

// Fused per-16-node block (R15-proven 63.6us, unchanged).
//  phase 1: 16 groups x 16 lanes x 1 node: register fp32 gather, unroll x4
//           (R3 lesson: unroll 8 -> VGPR 72 crosses 64-step, 43->25% occ).
//  phase 2: MFMA epilogue, 4 waves x 32 output cols, one 16-row tile.
// LDS ~7.5 KB, 256 thr -> thread-capped 8 blocks/CU; 3125 blocks = 12.2/CU.
__global__ __launch_bounds__(256) void bucket_fused(
    const u16* __restrict__ hx, const u16* __restrict__ r_bf,
    const u16* __restrict__ norm_bf, const float* __restrict__ b_f,
    const int* __restrict__ nodeBase, const int* __restrict__ spk,
    const u16* __restrict__ wt, const void* __restrict__ h, void* __restrict__ out)
{
    __shared__ int nb[BNF + 1];
    __shared__ int eidx[ECAP6];        // 3 KB
    __shared__ u16 Xu[BNF][136];       // 4.25 KB
    int tid = threadIdx.x;
    int b = blockIdx.x;
    if (tid <= BNF) nb[tid] = nodeBase[b * BNF + tid];
    __syncthreads();
    int bs = nb[0];
    int tot = nb[BNF] - bs; if (tot > ECAP6) tot = ECAP6;
    for (int i = tid; i < tot; i += 256) eidx[i] = spk[bs + i];
    __syncthreads();

    // ---- phase 1: register gather, 16 groups x 16 lanes, 1 node each
    int g = tid & 15, grp = tid >> 4;
    {
        int rs = nb[grp] - bs, re = nb[grp + 1] - bs;
        if (rs > ECAP6) rs = ECAP6;
        if (re > ECAP6) re = ECAP6;
        int cnt = re - rs;
        float acc[8] = {};
        int j = 0;
        for (; j + 3 < cnt; j += 4) {
            int pk0 = eidx[rs + j], pk1 = eidx[rs + j + 1];
            int pk2 = eidx[rs + j + 2], pk3 = eidx[rs + j + 3];
            short8 h0 = *(const short8*)(hx + (size_t)(pk0 & 0xFFFF) * DIM + g * 8);
            short8 h1 = *(const short8*)(hx + (size_t)(pk1 & 0xFFFF) * DIM + g * 8);
            short8 h2 = *(const short8*)(hx + (size_t)(pk2 & 0xFFFF) * DIM + g * 8);
            short8 h3 = *(const short8*)(hx + (size_t)(pk3 & 0xFFFF) * DIM + g * 8);
            short8 v0 = *(const short8*)(r_bf + (size_t)((pk0 >> 16) & 0xFF) * DIM + g * 8);
            short8 v1 = *(const short8*)(r_bf + (size_t)((pk1 >> 16) & 0xFF) * DIM + g * 8);
            short8 v2 = *(const short8*)(r_bf + (size_t)((pk2 >> 16) & 0xFF) * DIM + g * 8);
            short8 v3 = *(const short8*)(r_bf + (size_t)((pk3 >> 16) & 0xFF) * DIM + g * 8);
#pragma unroll
            for (int d = 0; d < 8; ++d) {
                acc[d] += (bf2f((u16)h0[d]) - bf2f((u16)v0[d]))
                        + (bf2f((u16)h1[d]) - bf2f((u16)v1[d]))
                        + (bf2f((u16)h2[d]) - bf2f((u16)v2[d]))
                        + (bf2f((u16)h3[d]) - bf2f((u16)v3[d]));
            }
        }
        for (; j < cnt; ++j) {
            int pk = eidx[rs + j];
            short8 hv = *(const short8*)(hx + (size_t)(pk & 0xFFFF) * DIM + g * 8);
            short8 rv = *(const short8*)(r_bf + (size_t)((pk >> 16) & 0xFF) * DIM + g * 8);
#pragma unroll
            for (int d = 0; d < 8; ++d) acc[d] += bf2f((u16)hv[d]) - bf2f((u16)rv[d]);
        }
        int node = b * BNF + grp;
        float nv = bf2f(norm_bf[node]);
        short8 o;
#pragma unroll
        for (int d = 0; d < 8; ++d) o[d] = (short)f2bf(acc[d] * nv);
        *(short8*)&Xu[grp][g * 8] = o;
    }
    __syncthreads();

    // ---- phase 2: MFMA epilogue. 4 waves x 32 output cols, one 16-row tile.
    int w = tid >> 6, lane = tid & 63;
    int m = lane & 15, quad = lane >> 4;
    int nodeA = b * BNF + m;           // 3125*16 == 50000: never OOB
    short8 a[8];
#pragma unroll
    for (int kb = 0; kb < 4; ++kb)
        a[kb] = *(const short8*)(hx + (size_t)nodeA * DIM + kb * 32 + quad * 8);
#pragma unroll
    for (int kb = 0; kb < 4; ++kb)
        a[4 + kb] = *(const short8*)&Xu[m][kb * 32 + quad * 8];
    int isf = sniff_fp32(h, tid);
#pragma unroll
    for (int ct = 0; ct < 2; ++ct) {
        int n0 = w * 32 + ct * 16;
        f32x4 c4 = {0.f, 0.f, 0.f, 0.f};
#pragma unroll
        for (int kb = 0; kb < 8; ++kb) {
            short8 bv = *(const short8*)(wt + (size_t)(n0 + m) * K2 + kb * 32 + quad * 8);
            c4 = __builtin_amdgcn_mfma_f32_16x16x32_bf16(a[kb], bv, c4, 0, 0, 0);
        }
        int col = n0 + m;
        float bb = b_f[col];
#pragma unroll
        for (int rg = 0; rg < 4; ++rg) {
            int n = b * BNF + quad * 4 + rg;
            float v = c4[rg] + bb;
            v = v > 0.f ? v : 0.f;
            if (isf) ((float*)out)[(size_t)n * DIM + col] = v;
            else     ((u16*)out)[(size_t)n * DIM + col] = f2bf(v);
        }
    }
}

static inline size_t alup(size_t x) { return (x + 255) & ~(size_t)255; }

extern "C" void kernel_launch(void* const* d_in, const int* in_sizes, int n_in,
                              void* d_out, int out_size, void* d_ws, size_t ws_size,
                              hipStream_t stream) {
    const void* h    = d_in[0];
    const void* r    = d_in[1];
    const void* norm = d_in[2];
    const int* src   = (const int*)d_in[3];
    const int* dst   = (const int*)d_in[4];
    const int* rel   = (const int*)d_in[5];
    const void* Wmsg = d_in[6];
    const void* W    = d_in[7];
    const void* b    = d_in[8];

    // ws layout (~17 MB of 256 MiB)
    char* p = (char*)d_ws;
    u16* hx       = (u16*)p;                 p += alup((size_t)N_NODES * DIM * 2);  // 12.8 MB
    u16* r_bf     = (u16*)p;                 p += alup((size_t)NREL * DIM * 2);
    u16* wt       = (u16*)p;                 p += alup((size_t)DIM * K2 * 2);
    u16* norm_bf  = (u16*)p;                 p += alup((size_t)N_NODES * 2);
    float* b_f    = (float*)p;               p += alup((size_t)DIM * 4);
    int* nodeCount = (int*)p;                p += alup((size_t)N_NODES * 4);        // 200 KB
    int* nodeBase  = (int*)p;                p += alup((size_t)(N_NODES + 64) * 4); // 200 KB
    int* cursor    = (int*)p;                p += alup((size_t)N_NODES * 4);        // 200 KB
    int* spk      = (int*)p;                 p += alup((size_t)N_EDGES * 4);        // 3.2 MB

    hipMemsetAsync(nodeCount, 0, (size_t)N_NODES * 4, stream);
    prep_hist<<<PREP_BLOCKS + HIST_BLOCKS, 256, 0, stream>>>(
        h, r, norm, W, Wmsg, b, dst, hx, r_bf, wt, norm_bf, b_f, nodeCount);
    node_scan<<<1, 1024, 0, stream>>>(nodeCount, nodeBase, cursor);
    scatter<<<(N_EDGES + SEB - 1) / SEB, 256, 0, stream>>>(dst, src, rel, cursor, spk);
    bucket_fused<<<NFB, 256, 0, stream>>>(
        hx, r_bf, norm_bf, b_f, nodeBase, spk, wt, h, d_out);
}

// Round 7
// 178.247 us; speedup vs baseline: 2.0806x; 2.0806x over previous
//
#include <hip/hip_runtime.h>

#define N_NODES 50000
#define N_EDGES 800000
#define DIM 128
#define K2 256          // concat K dimension (wt rows)
#define NREL 200
#define NB2 391         // coarse buckets of 128 nodes (49999>>7 = 390)
#define SLAB 3072       // slab slots per bucket (mean 2046, +22 sigma)
#define EPB 2048        // edges per fill block (512 thr x 4)
#define FILL_BLOCKS ((N_EDGES + EPB - 1) / EPB)   // 391
#define BNF 16          // nodes per fused block
#define NFB 3125        // fused blocks (50000/16)
#define ECAP6 768       // fused edge cache (16-node sum mean 256, +31 sigma)

typedef unsigned short u16;
typedef __attribute__((ext_vector_type(8))) short short8;   // 8 x bf16 = 4 VGPR
typedef __attribute__((ext_vector_type(4))) float f32x4;    // MFMA acc

__device__ __forceinline__ float bf2f(u16 v) {
    union { unsigned int u; float f; } x;
    x.u = ((unsigned int)v) << 16;
    return x.f;
}

__device__ __forceinline__ u16 f2bf(float f) {
    union { unsigned int u; float f; } x;
    x.f = f;
    return (u16)((x.u + 0x7FFFu + ((x.u >> 16) & 1u)) >> 16);  // RNE
}

// Per-wave dtype sniff (R2/R3-verified): fp32 inputs -> low mantissa halves
// parse as insane bf16 ~65%; bf16 N(0,1) data ~0%. Wave-uniform result.
__device__ __forceinline__ int sniff_fp32(const void* h, int tid) {
    const u16* hp = (const u16*)h;
    u16 v = hp[2 * (tid & 63)];
    float a = fabsf(bf2f(v));
    int insane = ((v & 0x7F80) == 0x7F80) || (a != 0.0f && (a > 1e6f || a < 1e-20f));
    return __popcll(__ballot(insane)) > 16;
}

// fused prep (R17: hist tail DELETED — slab allocation needs no counts;
// saves a full dst pass + 800K LDS atomics + 49K global atomics).
#define PREP_H (N_NODES * 32)
#define PREP_R (NREL * 32)
#define PREP_W 8192
#define PREP_N (N_NODES / 4)
#define PREP_B 32
#define PREP_TOT (PREP_H + PREP_R + PREP_W + PREP_N + PREP_B)
#define PREP_BLOCKS ((PREP_TOT + 255) / 256)
__global__ __launch_bounds__(256) void prep(
    const void* __restrict__ h, const void* __restrict__ r, const void* __restrict__ norm,
    const void* __restrict__ W, const void* __restrict__ Wmsg, const void* __restrict__ bias,
    u16* __restrict__ hx, u16* __restrict__ r_bf, u16* __restrict__ wt,
    u16* __restrict__ norm_bf, float* __restrict__ b_f)
{
    int tid = threadIdx.x;
    int isf = sniff_fp32(h, tid);
    int t = blockIdx.x * 256 + tid;
    if (t < PREP_H) {
        int n = t >> 5, c = t & 31;
        float4 v; float nv;
        if (isf) {
            nv = ((const float*)norm)[n];
            v = *(const float4*)((const float*)h + (size_t)n * DIM + c * 4);
        } else {
            nv = bf2f(((const u16*)norm)[n]);
            ushort4 u = *(const ushort4*)((const u16*)h + (size_t)n * DIM + c * 4);
            v = make_float4(bf2f(u.x), bf2f(u.y), bf2f(u.z), bf2f(u.w));
        }
        ushort4 o;
        o.x = f2bf(v.x * nv); o.y = f2bf(v.y * nv); o.z = f2bf(v.z * nv); o.w = f2bf(v.w * nv);
        *(ushort4*)(hx + (size_t)n * DIM + c * 4) = o;
    } else if (t < PREP_H + PREP_R) {
        int t2 = t - PREP_H;
        int rho = t2 >> 5, c = t2 & 31;
        float4 v;
        if (isf) v = *(const float4*)((const float*)r + (size_t)rho * DIM + c * 4);
        else {
            ushort4 u = *(const ushort4*)((const u16*)r + (size_t)rho * DIM + c * 4);
            v = make_float4(bf2f(u.x), bf2f(u.y), bf2f(u.z), bf2f(u.w));
        }
        ushort4 o;
        o.x = f2bf(v.x); o.y = f2bf(v.y); o.z = f2bf(v.z); o.w = f2bf(v.w);
        *(ushort4*)(r_bf + (size_t)rho * DIM + c * 4) = o;
    } else if (t < PREP_H + PREP_R + PREP_W) {
        int t3 = t - PREP_H - PREP_R;
        int j = t3 >> 6;
        int k0 = (t3 & 63) * 4;
        ushort4 o;
        u16* op = (u16*)&o;
        for (int kk = 0; kk < 4; ++kk) {
            int k = k0 + kk;
            float wv;
            if (isf) wv = (k < 128) ? ((const float*)W)[(size_t)k * DIM + j]
                                    : ((const float*)Wmsg)[(size_t)(k - 128) * DIM + j];
            else     wv = (k < 128) ? bf2f(((const u16*)W)[(size_t)k * DIM + j])
                                    : bf2f(((const u16*)Wmsg)[(size_t)(k - 128) * DIM + j]);
            op[kk] = f2bf(wv);
        }
        *(ushort4*)(wt + (size_t)j * K2 + k0) = o;
    } else if (t < PREP_H + PREP_R + PREP_W + PREP_N) {
        int n0 = (t - PREP_H - PREP_R - PREP_W) * 4;
        ushort4 o;
        if (isf) {
            float4 v = *(const float4*)((const float*)norm + n0);
            o.x = f2bf(v.x); o.y = f2bf(v.y); o.z = f2bf(v.z); o.w = f2bf(v.w);
        } else {
            o = *(const ushort4*)((const u16*)norm + n0);
        }
        *(ushort4*)(norm_bf + n0) = o;
    } else if (t < PREP_TOT) {
        int j0 = (t - PREP_H - PREP_R - PREP_W - PREP_N) * 4;
        float4 v;
        if (isf) v = *(const float4*)((const float*)bias + j0);
        else {
            ushort4 u = *(const ushort4*)((const u16*)bias + j0);
            v = make_float4(bf2f(u.x), bf2f(u.y), bf2f(u.z), bf2f(u.w));
        }
        *(float4*)(b_f + j0) = v;
    }
}

// R17: slab scatter. LDS presort by coarse bucket (proven R7 machinery), but
// destination = fixed per-bucket slab (b*SLAB + cursor[b] bump) -> needs NO
// hist pass and NO coarse scan. ONE 512-scan (local ranks) instead of three.
// ~55K returning atomics total. payload = src | rel<<16 | (dst&127)<<24
__global__ __launch_bounds__(512) void fill_slab(
    const int* __restrict__ dst, const int* __restrict__ src, const int* __restrict__ rel,
    int* __restrict__ cursor, int* __restrict__ spk1)
{
    __shared__ int hist[NB2];
    __shared__ int lbase[NB2];
    __shared__ int gbase[NB2];
    __shared__ int sd[512];
    __shared__ int pay[EPB];
    __shared__ u16 bkt[EPB];
    int tid = threadIdx.x;
    for (int i = tid; i < NB2; i += 512) hist[i] = 0;
    __syncthreads();
    int e0 = blockIdx.x * EPB;
    int myb[4], myr[4], myp[4];
#pragma unroll
    for (int i = 0; i < 4; ++i) {
        int e = e0 + i * 512 + tid;
        myb[i] = -1;
        if (e < N_EDGES) {
            int d = dst[e];
            int b = d >> 7;
            myb[i] = b;
            myr[i] = atomicAdd(&hist[b], 1);
            myp[i] = src[e] | (rel[e] << 16) | ((d & 127) << 24);
        }
    }
    __syncthreads();
    sd[tid] = (tid < NB2) ? hist[tid] : 0;
    __syncthreads();
    for (int off = 1; off < 512; off <<= 1) {
        int v = (tid >= off) ? sd[tid - off] : 0;
        __syncthreads();
        sd[tid] += v;
        __syncthreads();
    }
    if (tid < NB2) {
        lbase[tid] = sd[tid] - hist[tid];
        gbase[tid] = tid * SLAB + (hist[tid] ? atomicAdd(&cursor[tid], hist[tid]) : 0);
    }
    __syncthreads();
#pragma unroll
    for (int i = 0; i < 4; ++i) {
        if (myb[i] >= 0) {
            int lp = lbase[myb[i]] + myr[i];
            pay[lp] = myp[i];
            bkt[lp] = (u16)myb[i];
        }
    }
    __syncthreads();
    int total = N_EDGES - e0; if (total > EPB) total = EPB;
#pragma unroll
    for (int i = 0; i < 4; ++i) {
        int lp = i * 512 + tid;
        if (lp < total) {
            int b = bkt[lp];
            spk1[gbase[b] + (lp - lbase[b])] = pay[lp];
        }
    }
}

// R17: counting-sort slab -> compacted node-sorted spk2 + nodeBase[50001].
// Global base for bucket fb = reduce of cursor[0..fb) (391 L2-hot ints).
__global__ __launch_bounds__(512) void sort_fine(
    const int* __restrict__ cursor, const int* __restrict__ spk1,
    int* __restrict__ spk2, int* __restrict__ nodeBase)
{
    __shared__ int hist[128];
    __shared__ int lb[128];
    __shared__ int sd[512];
    __shared__ int sorted[SLAB];       // 12 KB
    int tid = threadIdx.x;
    int fb = blockIdx.x;
    // ---- base = sum of counts below fb (block-wide reduce)
    int acc = 0;
    for (int i = tid; i < NB2; i += 512)
        if (i < fb) acc += cursor[i];
    sd[tid] = acc;
    __syncthreads();
    for (int off = 256; off > 0; off >>= 1) {
        if (tid < off) sd[tid] += sd[tid + off];
        __syncthreads();
    }
    int base = sd[0];
    int size = cursor[fb];
    if (size > SLAB) size = SLAB;
    if (tid < 128) hist[tid] = 0;
    __syncthreads();
    // ---- load + rank (static-indexed regs, rule #20)
    int myp[6], myr[6], myd[6];
#pragma unroll
    for (int q = 0; q < 6; ++q) {
        int i = tid + q * 512;
        myd[q] = -1;
        if (i < size) {
            int pk = spk1[fb * SLAB + i];
            int dl = (pk >> 24) & 127;
            myp[q] = pk;
            myd[q] = dl;
            myr[q] = atomicAdd(&hist[dl], 1);
        }
    }
    __syncthreads();
    // ---- exclusive scan of 128 node counts
    if (tid < 128) sd[tid] = hist[tid];
    __syncthreads();
    for (int off = 1; off < 128; off <<= 1) {
        int v = 0;
        if (tid < 128 && tid >= off) v = sd[tid - off];
        __syncthreads();
        if (tid < 128) sd[tid] += v;
        __syncthreads();
    }
    if (tid < 128) lb[tid] = sd[tid] - hist[tid];
    __syncthreads();
    // ---- scatter to LDS, write compacted node-sorted
#pragma unroll
    for (int q = 0; q < 6; ++q)
        if (myd[q] >= 0) sorted[lb[myd[q]] + myr[q]] = myp[q];
    __syncthreads();
    for (int i = tid; i < size; i += 512) spk2[base + i] = sorted[i];
    if (tid < 128) {
        int node = fb * 128 + tid;
        if (node <= N_NODES) nodeBase[node] = base + lb[tid];
    }
    if (fb == 0 && tid == 0) nodeBase[N_NODES] = N_EDGES;
}

// Fused per-16-node block (R15-proven 63.6us, byte-identical; reads spk2).
//  phase 1: 16 groups x 16 lanes x 1 node: register fp32 gather, unroll x4
//           (R3 lesson: unroll 8 -> VGPR 72 crosses 64-step, 43->25% occ).
//  phase 2: MFMA epilogue, 4 waves x 32 output cols, one 16-row tile.
// LDS ~7.5 KB, 256 thr -> thread-capped 8 blocks/CU; 3125 blocks = 12.2/CU.
__global__ __launch_bounds__(256) void bucket_fused(
    const u16* __restrict__ hx, const u16* __restrict__ r_bf,
    const u16* __restrict__ norm_bf, const float* __restrict__ b_f,
    const int* __restrict__ nodeBase, const int* __restrict__ spk,
    const u16* __restrict__ wt, const void* __restrict__ h, void* __restrict__ out)
{
    __shared__ int nb[BNF + 1];
    __shared__ int eidx[ECAP6];        // 3 KB
    __shared__ u16 Xu[BNF][136];       // 4.25 KB
    int tid = threadIdx.x;
    int b = blockIdx.x;
    if (tid <= BNF) nb[tid] = nodeBase[b * BNF + tid];
    __syncthreads();
    int bs = nb[0];
    int tot = nb[BNF] - bs; if (tot > ECAP6) tot = ECAP6;
    for (int i = tid; i < tot; i += 256) eidx[i] = spk[bs + i];
    __syncthreads();

    // ---- phase 1: register gather, 16 groups x 16 lanes, 1 node each
    int g = tid & 15, grp = tid >> 4;
    {
        int rs = nb[grp] - bs, re = nb[grp + 1] - bs;
        if (rs > ECAP6) rs = ECAP6;
        if (re > ECAP6) re = ECAP6;
        int cnt = re - rs;
        float acc[8] = {};
        int j = 0;
        for (; j + 3 < cnt; j += 4) {
            int pk0 = eidx[rs + j], pk1 = eidx[rs + j + 1];
            int pk2 = eidx[rs + j + 2], pk3 = eidx[rs + j + 3];
            short8 h0 = *(const short8*)(hx + (size_t)(pk0 & 0xFFFF) * DIM + g * 8);
            short8 h1 = *(const short8*)(hx + (size_t)(pk1 & 0xFFFF) * DIM + g * 8);
            short8 h2 = *(const short8*)(hx + (size_t)(pk2 & 0xFFFF) * DIM + g * 8);
            short8 h3 = *(const short8*)(hx + (size_t)(pk3 & 0xFFFF) * DIM + g * 8);
            short8 v0 = *(const short8*)(r_bf + (size_t)((pk0 >> 16) & 0xFF) * DIM + g * 8);
            short8 v1 = *(const short8*)(r_bf + (size_t)((pk1 >> 16) & 0xFF) * DIM + g * 8);
            short8 v2 = *(const short8*)(r_bf + (size_t)((pk2 >> 16) & 0xFF) * DIM + g * 8);
            short8 v3 = *(const short8*)(r_bf + (size_t)((pk3 >> 16) & 0xFF) * DIM + g * 8);
#pragma unroll
            for (int d = 0; d < 8; ++d) {
                acc[d] += (bf2f((u16)h0[d]) - bf2f((u16)v0[d]))
                        + (bf2f((u16)h1[d]) - bf2f((u16)v1[d]))
                        + (bf2f((u16)h2[d]) - bf2f((u16)v2[d]))
                        + (bf2f((u16)h3[d]) - bf2f((u16)v3[d]));
            }
        }
        for (; j < cnt; ++j) {
            int pk = eidx[rs + j];
            short8 hv = *(const short8*)(hx + (size_t)(pk & 0xFFFF) * DIM + g * 8);
            short8 rv = *(const short8*)(r_bf + (size_t)((pk >> 16) & 0xFF) * DIM + g * 8);
#pragma unroll
            for (int d = 0; d < 8; ++d) acc[d] += bf2f((u16)hv[d]) - bf2f((u16)rv[d]);
        }
        int node = b * BNF + grp;
        float nv = bf2f(norm_bf[node]);
        short8 o;
#pragma unroll
        for (int d = 0; d < 8; ++d) o[d] = (short)f2bf(acc[d] * nv);
        *(short8*)&Xu[grp][g * 8] = o;
    }
    __syncthreads();

    // ---- phase 2: MFMA epilogue. 4 waves x 32 output cols, one 16-row tile.
    int w = tid >> 6, lane = tid & 63;
    int m = lane & 15, quad = lane >> 4;
    int nodeA = b * BNF + m;           // 3125*16 == 50000: never OOB
    short8 a[8];
#pragma unroll
    for (int kb = 0; kb < 4; ++kb)
        a[kb] = *(const short8*)(hx + (size_t)nodeA * DIM + kb * 32 + quad * 8);
#pragma unroll
    for (int kb = 0; kb < 4; ++kb)
        a[4 + kb] = *(const short8*)&Xu[m][kb * 32 + quad * 8];
    int isf = sniff_fp32(h, tid);
#pragma unroll
    for (int ct = 0; ct < 2; ++ct) {
        int n0 = w * 32 + ct * 16;
        f32x4 c4 = {0.f, 0.f, 0.f, 0.f};
#pragma unroll
        for (int kb = 0; kb < 8; ++kb) {
            short8 bv = *(const short8*)(wt + (size_t)(n0 + m) * K2 + kb * 32 + quad * 8);
            c4 = __builtin_amdgcn_mfma_f32_16x16x32_bf16(a[kb], bv, c4, 0, 0, 0);
        }
        int col = n0 + m;
        float bb = b_f[col];
#pragma unroll
        for (int rg = 0; rg < 4; ++rg) {
            int n = b * BNF + quad * 4 + rg;
            float v = c4[rg] + bb;
            v = v > 0.f ? v : 0.f;
            if (isf) ((float*)out)[(size_t)n * DIM + col] = v;
            else     ((u16*)out)[(size_t)n * DIM + col] = f2bf(v);
        }
    }
}

static inline size_t alup(size_t x) { return (x + 255) & ~(size_t)255; }

extern "C" void kernel_launch(void* const* d_in, const int* in_sizes, int n_in,
                              void* d_out, int out_size, void* d_ws, size_t ws_size,
                              hipStream_t stream) {
    const void* h    = d_in[0];
    const void* r    = d_in[1];
    const void* norm = d_in[2];
    const int* src   = (const int*)d_in[3];
    const int* dst   = (const int*)d_in[4];
    const int* rel   = (const int*)d_in[5];
    const void* Wmsg = d_in[6];
    const void* W    = d_in[7];
    const void* b    = d_in[8];

    // ws layout (~22 MB of 256 MiB)
    char* p = (char*)d_ws;
    u16* hx       = (u16*)p;                 p += alup((size_t)N_NODES * DIM * 2);  // 12.8 MB
    u16* r_bf     = (u16*)p;                 p += alup((size_t)NREL * DIM * 2);
    u16* wt       = (u16*)p;                 p += alup((size_t)DIM * K2 * 2);
    u16* norm_bf  = (u16*)p;                 p += alup((size_t)N_NODES * 2);
    float* b_f    = (float*)p;               p += alup((size_t)DIM * 4);
    int* cursor   = (int*)p;                 p += alup((size_t)NB2 * 4);
    int* nodeBase = (int*)p;                 p += alup((size_t)(N_NODES + 64) * 4); // 200 KB
    int* spk1     = (int*)p;                 p += alup((size_t)NB2 * SLAB * 4);     // 4.8 MB
    int* spk2     = (int*)p;                 p += alup((size_t)N_EDGES * 4);        // 3.2 MB

    hipMemsetAsync(cursor, 0, (size_t)NB2 * 4, stream);
    prep<<<PREP_BLOCKS, 256, 0, stream>>>(
        h, r, norm, W, Wmsg, b, hx, r_bf, wt, norm_bf, b_f);
    fill_slab<<<FILL_BLOCKS, 512, 0, stream>>>(dst, src, rel, cursor, spk1);
    sort_fine<<<NB2, 512, 0, stream>>>(cursor, spk1, spk2, nodeBase);
    bucket_fused<<<NFB, 256, 0, stream>>>(
        hx, r_bf, norm_bf, b_f, nodeBase, spk2, wt, h, d_out);
}

// Round 8
// 173.279 us; speedup vs baseline: 2.1402x; 1.0287x over previous
//
#include <hip/hip_runtime.h>

#define N_NODES 50000
#define N_EDGES 800000
#define DIM 128
#define K2 256          // concat K dimension (wt rows)
#define NREL 200
#define NB2 391         // coarse buckets of 128 nodes (49999>>7 = 390)
#define SLAB 3072       // slab slots per bucket (mean 2046, +22 sigma)
#define EPB 2048        // edges per fill block (512 thr x 4)
#define FILL_BLOCKS ((N_EDGES + EPB - 1) / EPB)   // 391
#define BNF 16          // nodes per fused block
#define NFB 3125        // fused blocks (50000/16)
#define ECAP6 768       // fused edge cache (16-node sum mean 256, +31 sigma)

typedef unsigned short u16;
typedef __attribute__((ext_vector_type(8))) short short8;   // 8 x bf16 = 4 VGPR
typedef __attribute__((ext_vector_type(4))) float f32x4;    // MFMA acc

__device__ __forceinline__ float bf2f(u16 v) {
    union { unsigned int u; float f; } x;
    x.u = ((unsigned int)v) << 16;
    return x.f;
}

__device__ __forceinline__ u16 f2bf(float f) {
    union { unsigned int u; float f; } x;
    x.f = f;
    return (u16)((x.u + 0x7FFFu + ((x.u >> 16) & 1u)) >> 16);  // RNE
}

// Per-wave dtype sniff (R2/R3-verified): fp32 inputs -> low mantissa halves
// parse as insane bf16 ~65%; bf16 N(0,1) data ~0%. Wave-uniform result.
__device__ __forceinline__ int sniff_fp32(const void* h, int tid) {
    const u16* hp = (const u16*)h;
    u16 v = hp[2 * (tid & 63)];
    float a = fabsf(bf2f(v));
    int insane = ((v & 0x7F80) == 0x7F80) || (a != 0.0f && (a > 1e6f || a < 1e-20f));
    return __popcll(__ballot(insane)) > 16;
}

// R18: prep and fill FUSED into one launch as disjoint block ranges.
// They touch disjoint data (h/r/W/norm/bias->hx/wt vs dst/src/rel->spk1),
// both memory-bound -> duration ~ max instead of sum, one launch gap saved.
// Fill blocks come FIRST in the grid (dispatch order).
#define PREP_H (N_NODES * 32)
#define PREP_R (NREL * 32)
#define PREP_W 8192
#define PREP_N (N_NODES / 4)
#define PREP_B 32
#define PREP_TOT (PREP_H + PREP_R + PREP_W + PREP_N + PREP_B)
#define PREP_BLK512 ((PREP_TOT + 511) / 512)
__global__ __launch_bounds__(512) void prep_fill(
    const void* __restrict__ h, const void* __restrict__ r, const void* __restrict__ norm,
    const void* __restrict__ W, const void* __restrict__ Wmsg, const void* __restrict__ bias,
    const int* __restrict__ dst, const int* __restrict__ src, const int* __restrict__ rel,
    u16* __restrict__ hx, u16* __restrict__ r_bf, u16* __restrict__ wt,
    u16* __restrict__ norm_bf, float* __restrict__ b_f,
    int* __restrict__ cursor, int* __restrict__ spk1)
{
    // fill-path LDS (allocated for all blocks; prep blocks ignore it)
    __shared__ int hist[NB2];
    __shared__ int lbase[NB2];
    __shared__ int gbase[NB2];
    __shared__ int sd[512];
    __shared__ int pay[EPB];
    __shared__ u16 bkt[EPB];
    int tid = threadIdx.x;

    if (blockIdx.x < FILL_BLOCKS) {     // ---------------- fill_slab (R17-proven)
        for (int i = tid; i < NB2; i += 512) hist[i] = 0;
        __syncthreads();
        int e0 = blockIdx.x * EPB;
        int myb[4], myr[4], myp[4];
#pragma unroll
        for (int i = 0; i < 4; ++i) {
            int e = e0 + i * 512 + tid;
            myb[i] = -1;
            if (e < N_EDGES) {
                int d = dst[e];
                int b = d >> 7;
                myb[i] = b;
                myr[i] = atomicAdd(&hist[b], 1);
                myp[i] = src[e] | (rel[e] << 16) | ((d & 127) << 24);
            }
        }
        __syncthreads();
        sd[tid] = (tid < NB2) ? hist[tid] : 0;
        __syncthreads();
        for (int off = 1; off < 512; off <<= 1) {
            int v = (tid >= off) ? sd[tid - off] : 0;
            __syncthreads();
            sd[tid] += v;
            __syncthreads();
        }
        if (tid < NB2) {
            lbase[tid] = sd[tid] - hist[tid];
            gbase[tid] = tid * SLAB + (hist[tid] ? atomicAdd(&cursor[tid], hist[tid]) : 0);
        }
        __syncthreads();
#pragma unroll
        for (int i = 0; i < 4; ++i) {
            if (myb[i] >= 0) {
                int lp = lbase[myb[i]] + myr[i];
                pay[lp] = myp[i];
                bkt[lp] = (u16)myb[i];
            }
        }
        __syncthreads();
        int total = N_EDGES - e0; if (total > EPB) total = EPB;
#pragma unroll
        for (int i = 0; i < 4; ++i) {
            int lp = i * 512 + tid;
            if (lp < total) {
                int b = bkt[lp];
                spk1[gbase[b] + (lp - lbase[b])] = pay[lp];
            }
        }
        return;
    }

    // ---------------- prep (R17-proven, 512-thread indexing)
    int isf = sniff_fp32(h, tid);
    int t = (blockIdx.x - FILL_BLOCKS) * 512 + tid;
    if (t < PREP_H) {
        int n = t >> 5, c = t & 31;
        float4 v; float nv;
        if (isf) {
            nv = ((const float*)norm)[n];
            v = *(const float4*)((const float*)h + (size_t)n * DIM + c * 4);
        } else {
            nv = bf2f(((const u16*)norm)[n]);
            ushort4 u = *(const ushort4*)((const u16*)h + (size_t)n * DIM + c * 4);
            v = make_float4(bf2f(u.x), bf2f(u.y), bf2f(u.z), bf2f(u.w));
        }
        ushort4 o;
        o.x = f2bf(v.x * nv); o.y = f2bf(v.y * nv); o.z = f2bf(v.z * nv); o.w = f2bf(v.w * nv);
        *(ushort4*)(hx + (size_t)n * DIM + c * 4) = o;
    } else if (t < PREP_H + PREP_R) {
        int t2 = t - PREP_H;
        int rho = t2 >> 5, c = t2 & 31;
        float4 v;
        if (isf) v = *(const float4*)((const float*)r + (size_t)rho * DIM + c * 4);
        else {
            ushort4 u = *(const ushort4*)((const u16*)r + (size_t)rho * DIM + c * 4);
            v = make_float4(bf2f(u.x), bf2f(u.y), bf2f(u.z), bf2f(u.w));
        }
        ushort4 o;
        o.x = f2bf(v.x); o.y = f2bf(v.y); o.z = f2bf(v.z); o.w = f2bf(v.w);
        *(ushort4*)(r_bf + (size_t)rho * DIM + c * 4) = o;
    } else if (t < PREP_H + PREP_R + PREP_W) {
        int t3 = t - PREP_H - PREP_R;
        int j = t3 >> 6;
        int k0 = (t3 & 63) * 4;
        ushort4 o;
        u16* op = (u16*)&o;
        for (int kk = 0; kk < 4; ++kk) {
            int k = k0 + kk;
            float wv;
            if (isf) wv = (k < 128) ? ((const float*)W)[(size_t)k * DIM + j]
                                    : ((const float*)Wmsg)[(size_t)(k - 128) * DIM + j];
            else     wv = (k < 128) ? bf2f(((const u16*)W)[(size_t)k * DIM + j])
                                    : bf2f(((const u16*)Wmsg)[(size_t)(k - 128) * DIM + j]);
            op[kk] = f2bf(wv);
        }
        *(ushort4*)(wt + (size_t)j * K2 + k0) = o;
    } else if (t < PREP_H + PREP_R + PREP_W + PREP_N) {
        int n0 = (t - PREP_H - PREP_R - PREP_W) * 4;
        ushort4 o;
        if (isf) {
            float4 v = *(const float4*)((const float*)norm + n0);
            o.x = f2bf(v.x); o.y = f2bf(v.y); o.z = f2bf(v.z); o.w = f2bf(v.w);
        } else {
            o = *(const ushort4*)((const u16*)norm + n0);
        }
        *(ushort4*)(norm_bf + n0) = o;
    } else if (t < PREP_TOT) {
        int j0 = (t - PREP_H - PREP_R - PREP_W - PREP_N) * 4;
        float4 v;
        if (isf) v = *(const float4*)((const float*)bias + j0);
        else {
            ushort4 u = *(const ushort4*)((const u16*)bias + j0);
            v = make_float4(bf2f(u.x), bf2f(u.y), bf2f(u.z), bf2f(u.w));
        }
        *(float4*)(b_f + j0) = v;
    }
}

// R17-proven: counting-sort slab -> compacted node-sorted spk2 + nodeBase[50001].
// Global base for bucket fb = reduce of cursor[0..fb) (391 L2-hot ints).
__global__ __launch_bounds__(512) void sort_fine(
    const int* __restrict__ cursor, const int* __restrict__ spk1,
    int* __restrict__ spk2, int* __restrict__ nodeBase)
{
    __shared__ int hist[128];
    __shared__ int lb[128];
    __shared__ int sd[512];
    __shared__ int sorted[SLAB];       // 12 KB
    int tid = threadIdx.x;
    int fb = blockIdx.x;
    // ---- base = sum of counts below fb (block-wide reduce)
    int acc = 0;
    for (int i = tid; i < NB2; i += 512)
        if (i < fb) acc += cursor[i];
    sd[tid] = acc;
    __syncthreads();
    for (int off = 256; off > 0; off >>= 1) {
        if (tid < off) sd[tid] += sd[tid + off];
        __syncthreads();
    }
    int base = sd[0];
    int size = cursor[fb];
    if (size > SLAB) size = SLAB;
    if (tid < 128) hist[tid] = 0;
    __syncthreads();
    // ---- load + rank (static-indexed regs, rule #20)
    int myp[6], myr[6], myd[6];
#pragma unroll
    for (int q = 0; q < 6; ++q) {
        int i = tid + q * 512;
        myd[q] = -1;
        if (i < size) {
            int pk = spk1[fb * SLAB + i];
            int dl = (pk >> 24) & 127;
            myp[q] = pk;
            myd[q] = dl;
            myr[q] = atomicAdd(&hist[dl], 1);
        }
    }
    __syncthreads();
    // ---- exclusive scan of 128 node counts
    if (tid < 128) sd[tid] = hist[tid];
    __syncthreads();
    for (int off = 1; off < 128; off <<= 1) {
        int v = 0;
        if (tid < 128 && tid >= off) v = sd[tid - off];
        __syncthreads();
        if (tid < 128) sd[tid] += v;
        __syncthreads();
    }
    if (tid < 128) lb[tid] = sd[tid] - hist[tid];
    __syncthreads();
    // ---- scatter to LDS, write compacted node-sorted
#pragma unroll
    for (int q = 0; q < 6; ++q)
        if (myd[q] >= 0) sorted[lb[myd[q]] + myr[q]] = myp[q];
    __syncthreads();
    for (int i = tid; i < size; i += 512) spk2[base + i] = sorted[i];
    if (tid < 128) {
        int node = fb * 128 + tid;
        if (node <= N_NODES) nodeBase[node] = base + lb[tid];
    }
    if (fb == 0 && tid == 0) nodeBase[N_NODES] = N_EDGES;
}

// Fused per-16-node block (R15-proven 63.6us, byte-identical; reads spk2).
//  phase 1: 16 groups x 16 lanes x 1 node: register fp32 gather, unroll x4
//           (R3 lesson: unroll 8 -> VGPR 72 crosses 64-step, 43->25% occ).
//  phase 2: MFMA epilogue, 4 waves x 32 output cols, one 16-row tile.
// LDS ~7.5 KB, 256 thr -> thread-capped 8 blocks/CU; 3125 blocks = 12.2/CU.
__global__ __launch_bounds__(256) void bucket_fused(
    const u16* __restrict__ hx, const u16* __restrict__ r_bf,
    const u16* __restrict__ norm_bf, const float* __restrict__ b_f,
    const int* __restrict__ nodeBase, const int* __restrict__ spk,
    const u16* __restrict__ wt, const void* __restrict__ h, void* __restrict__ out)
{
    __shared__ int nb[BNF + 1];
    __shared__ int eidx[ECAP6];        // 3 KB
    __shared__ u16 Xu[BNF][136];       // 4.25 KB
    int tid = threadIdx.x;
    int b = blockIdx.x;
    if (tid <= BNF) nb[tid] = nodeBase[b * BNF + tid];
    __syncthreads();
    int bs = nb[0];
    int tot = nb[BNF] - bs; if (tot > ECAP6) tot = ECAP6;
    for (int i = tid; i < tot; i += 256) eidx[i] = spk[bs + i];
    __syncthreads();

    // ---- phase 1: register gather, 16 groups x 16 lanes, 1 node each
    int g = tid & 15, grp = tid >> 4;
    {
        int rs = nb[grp] - bs, re = nb[grp + 1] - bs;
        if (rs > ECAP6) rs = ECAP6;
        if (re > ECAP6) re = ECAP6;
        int cnt = re - rs;
        float acc[8] = {};
        int j = 0;
        for (; j + 3 < cnt; j += 4) {
            int pk0 = eidx[rs + j], pk1 = eidx[rs + j + 1];
            int pk2 = eidx[rs + j + 2], pk3 = eidx[rs + j + 3];
            short8 h0 = *(const short8*)(hx + (size_t)(pk0 & 0xFFFF) * DIM + g * 8);
            short8 h1 = *(const short8*)(hx + (size_t)(pk1 & 0xFFFF) * DIM + g * 8);
            short8 h2 = *(const short8*)(hx + (size_t)(pk2 & 0xFFFF) * DIM + g * 8);
            short8 h3 = *(const short8*)(hx + (size_t)(pk3 & 0xFFFF) * DIM + g * 8);
            short8 v0 = *(const short8*)(r_bf + (size_t)((pk0 >> 16) & 0xFF) * DIM + g * 8);
            short8 v1 = *(const short8*)(r_bf + (size_t)((pk1 >> 16) & 0xFF) * DIM + g * 8);
            short8 v2 = *(const short8*)(r_bf + (size_t)((pk2 >> 16) & 0xFF) * DIM + g * 8);
            short8 v3 = *(const short8*)(r_bf + (size_t)((pk3 >> 16) & 0xFF) * DIM + g * 8);
#pragma unroll
            for (int d = 0; d < 8; ++d) {
                acc[d] += (bf2f((u16)h0[d]) - bf2f((u16)v0[d]))
                        + (bf2f((u16)h1[d]) - bf2f((u16)v1[d]))
                        + (bf2f((u16)h2[d]) - bf2f((u16)v2[d]))
                        + (bf2f((u16)h3[d]) - bf2f((u16)v3[d]));
            }
        }
        for (; j < cnt; ++j) {
            int pk = eidx[rs + j];
            short8 hv = *(const short8*)(hx + (size_t)(pk & 0xFFFF) * DIM + g * 8);
            short8 rv = *(const short8*)(r_bf + (size_t)((pk >> 16) & 0xFF) * DIM + g * 8);
#pragma unroll
            for (int d = 0; d < 8; ++d) acc[d] += bf2f((u16)hv[d]) - bf2f((u16)rv[d]);
        }
        int node = b * BNF + grp;
        float nv = bf2f(norm_bf[node]);
        short8 o;
#pragma unroll
        for (int d = 0; d < 8; ++d) o[d] = (short)f2bf(acc[d] * nv);
        *(short8*)&Xu[grp][g * 8] = o;
    }
    __syncthreads();

    // ---- phase 2: MFMA epilogue. 4 waves x 32 output cols, one 16-row tile.
    int w = tid >> 6, lane = tid & 63;
    int m = lane & 15, quad = lane >> 4;
    int nodeA = b * BNF + m;           // 3125*16 == 50000: never OOB
    short8 a[8];
#pragma unroll
    for (int kb = 0; kb < 4; ++kb)
        a[kb] = *(const short8*)(hx + (size_t)nodeA * DIM + kb * 32 + quad * 8);
#pragma unroll
    for (int kb = 0; kb < 4; ++kb)
        a[4 + kb] = *(const short8*)&Xu[m][kb * 32 + quad * 8];
    int isf = sniff_fp32(h, tid);
#pragma unroll
    for (int ct = 0; ct < 2; ++ct) {
        int n0 = w * 32 + ct * 16;
        f32x4 c4 = {0.f, 0.f, 0.f, 0.f};
#pragma unroll
        for (int kb = 0; kb < 8; ++kb) {
            short8 bv = *(const short8*)(wt + (size_t)(n0 + m) * K2 + kb * 32 + quad * 8);
            c4 = __builtin_amdgcn_mfma_f32_16x16x32_bf16(a[kb], bv, c4, 0, 0, 0);
        }
        int col = n0 + m;
        float bb = b_f[col];
#pragma unroll
        for (int rg = 0; rg < 4; ++rg) {
            int n = b * BNF + quad * 4 + rg;
            float v = c4[rg] + bb;
            v = v > 0.f ? v : 0.f;
            if (isf) ((float*)out)[(size_t)n * DIM + col] = v;
            else     ((u16*)out)[(size_t)n * DIM + col] = f2bf(v);
        }
    }
}

static inline size_t alup(size_t x) { return (x + 255) & ~(size_t)255; }

extern "C" void kernel_launch(void* const* d_in, const int* in_sizes, int n_in,
                              void* d_out, int out_size, void* d_ws, size_t ws_size,
                              hipStream_t stream) {
    const void* h    = d_in[0];
    const void* r    = d_in[1];
    const void* norm = d_in[2];
    const int* src   = (const int*)d_in[3];
    const int* dst   = (const int*)d_in[4];
    const int* rel   = (const int*)d_in[5];
    const void* Wmsg = d_in[6];
    const void* W    = d_in[7];
    const void* b    = d_in[8];

    // ws layout (~22 MB of 256 MiB)
    char* p = (char*)d_ws;
    u16* hx       = (u16*)p;                 p += alup((size_t)N_NODES * DIM * 2);  // 12.8 MB
    u16* r_bf     = (u16*)p;                 p += alup((size_t)NREL * DIM * 2);
    u16* wt       = (u16*)p;                 p += alup((size_t)DIM * K2 * 2);
    u16* norm_bf  = (u16*)p;                 p += alup((size_t)N_NODES * 2);
    float* b_f    = (float*)p;               p += alup((size_t)DIM * 4);
    int* cursor   = (int*)p;                 p += alup((size_t)NB2 * 4);
    int* nodeBase = (int*)p;                 p += alup((size_t)(N_NODES + 64) * 4); // 200 KB
    int* spk1     = (int*)p;                 p += alup((size_t)NB2 * SLAB * 4);     // 4.8 MB
    int* spk2     = (int*)p;                 p += alup((size_t)N_EDGES * 4);        // 3.2 MB

    hipMemsetAsync(cursor, 0, (size_t)NB2 * 4, stream);
    prep_fill<<<FILL_BLOCKS + PREP_BLK512, 512, 0, stream>>>(
        h, r, norm, W, Wmsg, b, dst, src, rel,
        hx, r_bf, wt, norm_bf, b_f, cursor, spk1);
    sort_fine<<<NB2, 512, 0, stream>>>(cursor, spk1, spk2, nodeBase);
    bucket_fused<<<NFB, 256, 0, stream>>>(
        hx, r_bf, norm_bf, b_f, nodeBase, spk2, wt, h, d_out);
}